// Round 13
// baseline (94.711 us; speedup 1.0000x reference)
//
#include <hip/hip_runtime.h>

// DNA transport NEGF: per (b,e) invert A = (E*I - H) + i*diag(0.5*(gL+gR)),
// DOS = -Im tr(Gr), T = sum_ij gL_i gR_j |Gr_ij|^2, plus H scatter output.
//
// R10 TRIANGULAR GJ (validated, absmax 1.95e-3): complex-symmetric no-pivot
// GJ keeps M[i][j] = +-M[j][i] -> store only rows 0..j per column. 5 lanes
// per matrix, lane m owns cols j = 5c+m; 12 matrices/wave; pivot-COLUMN
// broadcast makes updates sign-free; row k updated uniformly and fixed after.
//
// R12 REGISTER DIET: R10/R11 lived at ~146 VGPRs -> HW granule {64,128,256}
// rounds to 256 -> 2 waves/SIMD (28% occupancy, both rounds identical).
// Operands are irreducible (50 complex pairs = 100); clobbers cut 36 -> 21:
// 2-deep quad window v0-7 (re-issue after consumption, WAR-safe in-order DS),
// p computed in-place over pivot (v8:9), den v10, t0-t3 = v12-19 (EX reads
// land directly), TM reuses temp pair v10:11 twice + scalar v20. Total ~128.
// amdgpu_waves_per_eu(4) pins the allocator to the 128-reg budget ->
// 4 waves/SIMD. DS waits: PCHAIN lgkmcnt(c*+3), WAITEX 2, ALLQ 1-ladder.
//
// No pivoting: imag(x^* A x) > 0 for all leading blocks => pivots bounded
// below by min_i 0.5(gL_i+gR_i). Stable in fp32 (R0-R11: absmax <= 3.9e-3).

typedef float f32x2 __attribute__((ext_vector_type(2)));

#define H_N   20
#define NE    100
#define T_OFF 0
#define D_OFF 102400
#define H_OFF 204800

__device__ __forceinline__ int triIdx(int i, int j) {  // i <= j, row-major triu
    return i * H_N - ((i * (i - 1)) >> 1) + (j - i);
}

// ---------------- asm building blocks ----------------
// v0:3 / v4:7 rotating quad window; v8:9 pivot -> p (in-place); v10 den /
// v10:11 TM temp; v12:13 t0, v14:15 t1, v16:17 t2, v18:19 t3; v20 scalar.
// s[90:91] exec save.

#define WSLOT(AK, OFF) "ds_write_b64 %[abm], %[" #AK "] offset:" #OFF "\n\t"
#define WMIX(AK, OFF, MS) \
  "v_cmp_lt_u32 vcc, " #MS ", %[vm]\n\t" \
  "s_and_saveexec_b64 s[90:91], vcc\n\t" \
  "ds_write_b64 %[abm], %[" #AK "] offset:" #OFF "\n\t" \
  "s_mov_b64 exec, s[90:91]\n\t"
#define BSTB(MS) \
  "v_cmp_eq_u32 vcc, " #MS ", %[vm]\n\t" \
  "s_and_saveexec_b64 s[90:91], vcc\n\t"
#define BSTE "s_mov_b64 exec, s[90:91]\n\t"
#define BW(AK, OFF) "ds_write_b64 %[ab], %[" #AK "] offset:" #OFF "\n\t"
#define PIV(OFF) "ds_read_b64 v[8:9], %[ab] offset:" #OFF "\n\t"
#define EXR(T0, T1, OFF) "ds_read_b64 v[" #T0 ":" #T1 "], %[abm] offset:" #OFF "\n\t"
#define EX0 EXR(12,13,0)
#define EX1 EX0 EXR(14,15,40)
#define EX2 EX1 EXR(16,17,80)
#define EX3 EX2 EXR(18,19,120)
#define QISS2 \
  "ds_read_b128 v[0:3], %[ab] offset:0\n\t" \
  "ds_read_b128 v[4:7], %[ab] offset:16\n\t"
// wait pivot (outstanding after = (c*+1) EX + 2 quads), reciprocal in-place
#define PCHAIN(WP) \
  "s_waitcnt lgkmcnt(" #WP ")\n\t" \
  "v_mul_f32 v10, v8, v8\n\t" \
  "v_fmac_f32 v10, v9, v9\n\t" \
  "v_rcp_f32 v10, v10\n\t" \
  "s_nop 1\n\t" \
  "v_mul_f32 v8, v8, v10\n\t" \
  "v_mul_f32 v9, -v9, v10\n\t"
// t = cmul(A[k], p), computed in-place in t (no temp)
#define TP(T0, T1, AK) \
  "v_pk_mul_f32 v[" #T0 ":" #T1 "], %[" #AK "], v[8:9] op_sel:[1,1] op_sel_hi:[1,0] neg_lo:[1,0]\n\t" \
  "v_pk_fma_f32 v[" #T0 ":" #T1 "], %[" #AK "], v[8:9], v[" #T0 ":" #T1 "] op_sel_hi:[0,1,1]\n\t"
// t = cmul(-e, p), e preloaded in t (temp v10:11)
#define TN(T0, T1) \
  "v_pk_mul_f32 v[10:11], v[" #T0 ":" #T1 "], v[8:9] op_sel:[1,1] op_sel_hi:[1,0] neg_hi:[1,0]\n\t" \
  "v_pk_fma_f32 v[" #T0 ":" #T1 "], v[" #T0 ":" #T1 "], v[8:9], v[10:11] op_sel_hi:[0,1,1] neg_lo:[1,0,0] neg_hi:[1,0,0]\n\t"
// mixed slot c*: TN first, TP-version in-place in v10:11, select, owner fix
#define TM(T0, T1, AK, MS) \
  TN(T0, T1) \
  "v_pk_mul_f32 v[10:11], %[" #AK "], v[8:9] op_sel:[1,1] op_sel_hi:[1,0] neg_lo:[1,0]\n\t" \
  "v_pk_fma_f32 v[10:11], %[" #AK "], v[8:9], v[10:11] op_sel_hi:[0,1,1]\n\t" \
  "v_cmp_lt_u32 vcc, " #MS ", %[vm]\n\t" \
  "v_cndmask_b32 v" #T0 ", v" #T0 ", v10, vcc\n\t" \
  "v_cndmask_b32 v" #T1 ", v" #T1 ", v11, vcc\n\t" \
  "v_add_f32 v20, 1.0, v8\n\t" \
  "v_cmp_eq_u32 vcc, " #MS ", %[vm]\n\t" \
  "v_cndmask_b32 v" #T0 ", v" #T0 ", v20, vcc\n\t" \
  "v_cndmask_b32 v" #T1 ", v" #T1 ", v9, vcc\n\t"
#define WAITEX "s_waitcnt lgkmcnt(2)\n\t"
#define PSET(AK, T0, T1) \
  "v_pk_mul_f32 %[" #AK "], v[" #T0 ":" #T1 "], 1.0 op_sel_hi:[1,0]\n\t"
#define POWN(AK, T0, T1, MS) \
  "v_cmp_eq_u32 vcc, " #MS ", %[vm]\n\t" \
  "v_cndmask_b32 v" #T0 ", v" #T0 ", v8, vcc\n\t" \
  "v_cndmask_b32 v" #T1 ", v" #T1 ", v9, vcc\n\t" \
  PSET(AK, T0, T1)
#define U(A, Y0, Y1, T0, T1) \
  "v_pk_fma_f32 %[" #A "], v[" #Y0 ":" #Y1 "], v[" #T0 ":" #T1 "], %[" #A "] op_sel:[1,1,0] op_sel_hi:[1,0,1] neg_hi:[1,0,0]\n\t" \
  "v_pk_fma_f32 %[" #A "], v[" #Y0 ":" #Y1 "], v[" #T0 ":" #T1 "], %[" #A "] op_sel_hi:[0,1,1] neg_lo:[1,0,0] neg_hi:[1,0,0]\n\t"

#define BUA0 BW(a0_0,0)
#define BUA1 BUA0 BW(a0_1,8)
#define BUA2 BUA1 BW(a0_2,16)
#define BUA3 BUA2 BW(a0_3,24)
#define BUA4 BUA3 BW(a0_4,32)
#define BUB4 BW(a1_0,0) BW(a1_1,8) BW(a1_2,16) BW(a1_3,24) BW(a1_4,32)
#define BUB5 BUB4 BW(a1_5,40)
#define BUB6 BUB5 BW(a1_6,48)
#define BUB7 BUB6 BW(a1_7,56)
#define BUB8 BUB7 BW(a1_8,64)
#define BUB9 BUB8 BW(a1_9,72)
#define BUC9 BW(a2_0,0) BW(a2_1,8) BW(a2_2,16) BW(a2_3,24) BW(a2_4,32) \
             BW(a2_5,40) BW(a2_6,48) BW(a2_7,56) BW(a2_8,64) BW(a2_9,72)
#define BUC10 BUC9 BW(a2_10,80)
#define BUC11 BUC10 BW(a2_11,88)
#define BUC12 BUC11 BW(a2_12,96)
#define BUC13 BUC12 BW(a2_13,104)
#define BUC14 BUC13 BW(a2_14,112)
#define BUD14 BW(a3_0,0) BW(a3_1,8) BW(a3_2,16) BW(a3_3,24) BW(a3_4,32) \
              BW(a3_5,40) BW(a3_6,48) BW(a3_7,56) BW(a3_8,64) BW(a3_9,72) \
              BW(a3_10,80) BW(a3_11,88) BW(a3_12,96) BW(a3_13,104) BW(a3_14,112)
#define BUD15 BUD14 BW(a3_15,120)
#define BUD16 BUD15 BW(a3_16,128)
#define BUD17 BUD16 BW(a3_17,136)
#define BUD18 BUD17 BW(a3_18,144)
#define BUD19 BUD18 BW(a3_19,152)

// 50 row-updates, 2-deep rotating window, counted waits, re-issue after use
#define ALLQ \
  "s_waitcnt lgkmcnt(1)\n\t" \
  U(a3_0,0,1,18,19) U(a3_1,2,3,18,19) U(a2_0,0,1,16,17) U(a2_1,2,3,16,17) \
  U(a1_0,0,1,14,15) U(a1_1,2,3,14,15) U(a0_0,0,1,12,13) U(a0_1,2,3,12,13) \
  "ds_read_b128 v[0:3], %[ab] offset:32\n\t" \
  "s_waitcnt lgkmcnt(1)\n\t" \
  U(a3_2,4,5,18,19) U(a3_3,6,7,18,19) U(a2_2,4,5,16,17) U(a2_3,6,7,16,17) \
  U(a1_2,4,5,14,15) U(a1_3,6,7,14,15) U(a0_2,4,5,12,13) U(a0_3,6,7,12,13) \
  "ds_read_b128 v[4:7], %[ab] offset:48\n\t" \
  "s_waitcnt lgkmcnt(1)\n\t" \
  U(a3_4,0,1,18,19) U(a3_5,2,3,18,19) U(a2_4,0,1,16,17) U(a2_5,2,3,16,17) \
  U(a1_4,0,1,14,15) U(a1_5,2,3,14,15) U(a0_4,0,1,12,13) \
  "ds_read_b128 v[0:3], %[ab] offset:64\n\t" \
  "s_waitcnt lgkmcnt(1)\n\t" \
  U(a3_6,4,5,18,19) U(a3_7,6,7,18,19) U(a2_6,4,5,16,17) U(a2_7,6,7,16,17) \
  U(a1_6,4,5,14,15) U(a1_7,6,7,14,15) \
  "ds_read_b128 v[4:7], %[ab] offset:80\n\t" \
  "s_waitcnt lgkmcnt(1)\n\t" \
  U(a3_8,0,1,18,19) U(a3_9,2,3,18,19) U(a2_8,0,1,16,17) U(a2_9,2,3,16,17) \
  U(a1_8,0,1,14,15) U(a1_9,2,3,14,15) \
  "ds_read_b128 v[0:3], %[ab] offset:96\n\t" \
  "s_waitcnt lgkmcnt(1)\n\t" \
  U(a3_10,4,5,18,19) U(a3_11,6,7,18,19) U(a2_10,4,5,16,17) U(a2_11,6,7,16,17) \
  "ds_read_b128 v[4:7], %[ab] offset:112\n\t" \
  "s_waitcnt lgkmcnt(1)\n\t" \
  U(a3_12,0,1,18,19) U(a3_13,2,3,18,19) U(a2_12,0,1,16,17) U(a2_13,2,3,16,17) \
  "ds_read_b128 v[0:3], %[ab] offset:128\n\t" \
  "s_waitcnt lgkmcnt(1)\n\t" \
  U(a3_14,4,5,18,19) U(a3_15,6,7,18,19) U(a2_14,4,5,16,17) \
  "ds_read_b128 v[4:7], %[ab] offset:144\n\t" \
  "s_waitcnt lgkmcnt(1)\n\t" \
  U(a3_16,0,1,18,19) U(a3_17,2,3,18,19) \
  "s_waitcnt lgkmcnt(0)\n\t" \
  U(a3_18,4,5,18,19) U(a3_19,6,7,18,19)

#define S0  WSLOT(a1_0,40) WSLOT(a2_0,80) WSLOT(a3_0,120) WMIX(a0_0,0,0) BSTB(0) BUA0 BSTE PIV(0)  EX0 QISS2 PCHAIN(3) TP(14,15,a1_0) TP(16,17,a2_0) TP(18,19,a3_0) WAITEX TM(12,13,a0_0,0) ALLQ PSET(a1_0,14,15) PSET(a2_0,16,17) PSET(a3_0,18,19) POWN(a0_0,12,13,0)
#define S1  WSLOT(a1_1,40) WSLOT(a2_1,80) WSLOT(a3_1,120) WMIX(a0_1,0,1) BSTB(1) BUA1 BSTE PIV(8)  EX0 QISS2 PCHAIN(3) TP(14,15,a1_1) TP(16,17,a2_1) TP(18,19,a3_1) WAITEX TM(12,13,a0_1,1) ALLQ PSET(a1_1,14,15) PSET(a2_1,16,17) PSET(a3_1,18,19) POWN(a0_1,12,13,1)
#define S2  WSLOT(a1_2,40) WSLOT(a2_2,80) WSLOT(a3_2,120) WMIX(a0_2,0,2) BSTB(2) BUA2 BSTE PIV(16) EX0 QISS2 PCHAIN(3) TP(14,15,a1_2) TP(16,17,a2_2) TP(18,19,a3_2) WAITEX TM(12,13,a0_2,2) ALLQ PSET(a1_2,14,15) PSET(a2_2,16,17) PSET(a3_2,18,19) POWN(a0_2,12,13,2)
#define S3  WSLOT(a1_3,40) WSLOT(a2_3,80) WSLOT(a3_3,120) WMIX(a0_3,0,3) BSTB(3) BUA3 BSTE PIV(24) EX0 QISS2 PCHAIN(3) TP(14,15,a1_3) TP(16,17,a2_3) TP(18,19,a3_3) WAITEX TM(12,13,a0_3,3) ALLQ PSET(a1_3,14,15) PSET(a2_3,16,17) PSET(a3_3,18,19) POWN(a0_3,12,13,3)
#define S4  WSLOT(a1_4,40) WSLOT(a2_4,80) WSLOT(a3_4,120)                BSTB(4) BUA4 BSTE PIV(32) EX0 QISS2 PCHAIN(3) TP(14,15,a1_4) TP(16,17,a2_4) TP(18,19,a3_4) WAITEX TM(12,13,a0_4,4) ALLQ PSET(a1_4,14,15) PSET(a2_4,16,17) PSET(a3_4,18,19) POWN(a0_4,12,13,4)
#define S5  WSLOT(a2_5,80) WSLOT(a3_5,120) WMIX(a1_5,40,0) BSTB(0) BUB5 BSTE PIV(40) EX1 QISS2 PCHAIN(4) TP(16,17,a2_5) TP(18,19,a3_5) WAITEX TN(12,13) TM(14,15,a1_5,0) ALLQ PSET(a2_5,16,17) PSET(a3_5,18,19) POWN(a1_5,14,15,0)
#define S6  WSLOT(a2_6,80) WSLOT(a3_6,120) WMIX(a1_6,40,1) BSTB(1) BUB6 BSTE PIV(48) EX1 QISS2 PCHAIN(4) TP(16,17,a2_6) TP(18,19,a3_6) WAITEX TN(12,13) TM(14,15,a1_6,1) ALLQ PSET(a2_6,16,17) PSET(a3_6,18,19) POWN(a1_6,14,15,1)
#define S7  WSLOT(a2_7,80) WSLOT(a3_7,120) WMIX(a1_7,40,2) BSTB(2) BUB7 BSTE PIV(56) EX1 QISS2 PCHAIN(4) TP(16,17,a2_7) TP(18,19,a3_7) WAITEX TN(12,13) TM(14,15,a1_7,2) ALLQ PSET(a2_7,16,17) PSET(a3_7,18,19) POWN(a1_7,14,15,2)
#define S8  WSLOT(a2_8,80) WSLOT(a3_8,120) WMIX(a1_8,40,3) BSTB(3) BUB8 BSTE PIV(64) EX1 QISS2 PCHAIN(4) TP(16,17,a2_8) TP(18,19,a3_8) WAITEX TN(12,13) TM(14,15,a1_8,3) ALLQ PSET(a2_8,16,17) PSET(a3_8,18,19) POWN(a1_8,14,15,3)
#define S9  WSLOT(a2_9,80) WSLOT(a3_9,120)                 BSTB(4) BUB9 BSTE PIV(72) EX1 QISS2 PCHAIN(4) TP(16,17,a2_9) TP(18,19,a3_9) WAITEX TN(12,13) TM(14,15,a1_9,4) ALLQ PSET(a2_9,16,17) PSET(a3_9,18,19) POWN(a1_9,14,15,4)
#define S10 WSLOT(a3_10,120) WMIX(a2_10,80,0) BSTB(0) BUC10 BSTE PIV(80)  EX2 QISS2 PCHAIN(5) TP(18,19,a3_10) WAITEX TN(12,13) TN(14,15) TM(16,17,a2_10,0) ALLQ PSET(a3_10,18,19) POWN(a2_10,16,17,0)
#define S11 WSLOT(a3_11,120) WMIX(a2_11,80,1) BSTB(1) BUC11 BSTE PIV(88)  EX2 QISS2 PCHAIN(5) TP(18,19,a3_11) WAITEX TN(12,13) TN(14,15) TM(16,17,a2_11,1) ALLQ PSET(a3_11,18,19) POWN(a2_11,16,17,1)
#define S12 WSLOT(a3_12,120) WMIX(a2_12,80,2) BSTB(2) BUC12 BSTE PIV(96)  EX2 QISS2 PCHAIN(5) TP(18,19,a3_12) WAITEX TN(12,13) TN(14,15) TM(16,17,a2_12,2) ALLQ PSET(a3_12,18,19) POWN(a2_12,16,17,2)
#define S13 WSLOT(a3_13,120) WMIX(a2_13,80,3) BSTB(3) BUC13 BSTE PIV(104) EX2 QISS2 PCHAIN(5) TP(18,19,a3_13) WAITEX TN(12,13) TN(14,15) TM(16,17,a2_13,3) ALLQ PSET(a3_13,18,19) POWN(a2_13,16,17,3)
#define S14 WSLOT(a3_14,120)                  BSTB(4) BUC14 BSTE PIV(112) EX2 QISS2 PCHAIN(5) TP(18,19,a3_14) WAITEX TN(12,13) TN(14,15) TM(16,17,a2_14,4) ALLQ PSET(a3_14,18,19) POWN(a2_14,16,17,4)
#define S15 WMIX(a3_15,120,0) BSTB(0) BUD15 BSTE PIV(120) EX3 QISS2 PCHAIN(6) WAITEX TN(12,13) TN(14,15) TN(16,17) TM(18,19,a3_15,0) ALLQ POWN(a3_15,18,19,0)
#define S16 WMIX(a3_16,120,1) BSTB(1) BUD16 BSTE PIV(128) EX3 QISS2 PCHAIN(6) WAITEX TN(12,13) TN(14,15) TN(16,17) TM(18,19,a3_16,1) ALLQ POWN(a3_16,18,19,1)
#define S17 WMIX(a3_17,120,2) BSTB(2) BUD17 BSTE PIV(136) EX3 QISS2 PCHAIN(6) WAITEX TN(12,13) TN(14,15) TN(16,17) TM(18,19,a3_17,2) ALLQ POWN(a3_17,18,19,2)
#define S18 WMIX(a3_18,120,3) BSTB(3) BUD18 BSTE PIV(144) EX3 QISS2 PCHAIN(6) WAITEX TN(12,13) TN(14,15) TN(16,17) TM(18,19,a3_18,3) ALLQ POWN(a3_18,18,19,3)
#define S19                   BSTB(4) BUD19 BSTE PIV(152) EX3 QISS2 PCHAIN(6) WAITEX TN(12,13) TN(14,15) TN(16,17) TM(18,19,a3_19,4) ALLQ POWN(a3_19,18,19,4)

__global__ __launch_bounds__(256)
__attribute__((amdgpu_waves_per_eu(4)))
void negf_all(const float* __restrict__ tri,
              const float* __restrict__ GL,
              const float* __restrict__ GR,
              float* __restrict__ out)
{
    // 4 independent waves/block, each with a private 1024-float LDS slice:
    // [0,400) Hcm col-major | [400,420) sgL | [420,440) sgR | [448,976) stage
    __shared__ __align__(16) float lds[4][1024];

    const int tid  = threadIdx.x;
    const int wid  = tid >> 6;
    const int lane = tid & 63;
    const int w    = blockIdx.x * 4 + wid;     // wave unit: (b, chunk)
    const int b    = w / 9;
    const int chunk = w - b * 9;

    float* const Hcm   = &lds[wid][0];
    float* const sgL   = &lds[wid][400];
    float* const sgR   = &lds[wid][420];
    float* const stage = &lds[wid][448];

    // ---- per-wave staging of H (col-major) + gammas ----
    const float* triB = tri + b * 210;
    for (int u = lane; u < 400; u += 64) {
        int c = u / 20, r = u - c * 20;
        int lo = r < c ? r : c;
        int hi = r < c ? c : r;
        Hcm[u] = triB[triIdx(lo, hi)];
    }
    if (lane < H_N) { sgL[lane] = GL[b * H_N + lane]; sgR[lane] = GR[b * H_N + lane]; }
    asm volatile("s_waitcnt lgkmcnt(0)" ::: "memory");   // wave-coherent LDS

    // ---- H output (row-major, exact copy); one wave per b ----
    if (chunk == 0) {
        for (int u = lane; u < 400; u += 64) {
            int r = u / 20, c = u - r * 20;
            out[H_OFF + b * 400 + u] = Hcm[c * 20 + r];
        }
    }

    const int sgw = lane / 5;                  // 0..11 active, 12 idle (60-63)
    const int m   = lane - sgw * 5;            // 0..4
    const int e   = chunk * 12 + sgw;
    if (sgw >= 12 || e >= NE) return;

    const int j0 = m, j1 = 5 + m, j2 = 10 + m, j3 = 15 + m;
    const float gam0 = 0.5f * (sgL[j0] + sgR[j0]);
    const float gam1 = 0.5f * (sgL[j1] + sgR[j1]);
    const float gam2 = 0.5f * (sgL[j2] + sgR[j2]);
    const float gam3 = 0.5f * (sgL[j3] + sgR[j3]);
    const float E = fmaf((float)e, 6.0f / 99.0f, -3.0f);

    // ---- init triangle columns (invalid rows -> 0, kept finite) ----
    f32x2 A0[5], A1[10], A2[15], A3[20];
#define MK(DST, I, J, G) { \
        float h = Hcm[(J) * 20 + (I)]; \
        bool vl = (I) <= (J); bool dg = (I) == (J); \
        DST.x = vl ? (dg ? (E - h) : -h) : 0.0f; \
        DST.y = vl ? (dg ? (G) : 0.0f) : 0.0f; }
    #pragma unroll
    for (int i = 0; i < 5;  ++i) MK(A0[i], i, j0, gam0)
    #pragma unroll
    for (int i = 0; i < 10; ++i) MK(A1[i], i, j1, gam1)
    #pragma unroll
    for (int i = 0; i < 15; ++i) MK(A2[i], i, j2, gam2)
    #pragma unroll
    for (int i = 0; i < 20; ++i) MK(A3[i], i, j3, gam3)
#undef MK

    const unsigned ab  = (unsigned)(size_t)&stage[sgw * 44];
    const unsigned abm = ab + 8u * (unsigned)m;
    const unsigned vmu = (unsigned)m;

    asm volatile(
        "s_waitcnt lgkmcnt(0)\n\t"
        S0 S1 S2 S3 S4 S5 S6 S7 S8 S9
        S10 S11 S12 S13 S14 S15 S16 S17 S18 S19
        : [a0_0]"+v"(A0[0]), [a0_1]"+v"(A0[1]), [a0_2]"+v"(A0[2]), [a0_3]"+v"(A0[3]), [a0_4]"+v"(A0[4]),
          [a1_0]"+v"(A1[0]), [a1_1]"+v"(A1[1]), [a1_2]"+v"(A1[2]), [a1_3]"+v"(A1[3]), [a1_4]"+v"(A1[4]),
          [a1_5]"+v"(A1[5]), [a1_6]"+v"(A1[6]), [a1_7]"+v"(A1[7]), [a1_8]"+v"(A1[8]), [a1_9]"+v"(A1[9]),
          [a2_0]"+v"(A2[0]), [a2_1]"+v"(A2[1]), [a2_2]"+v"(A2[2]), [a2_3]"+v"(A2[3]), [a2_4]"+v"(A2[4]),
          [a2_5]"+v"(A2[5]), [a2_6]"+v"(A2[6]), [a2_7]"+v"(A2[7]), [a2_8]"+v"(A2[8]), [a2_9]"+v"(A2[9]),
          [a2_10]"+v"(A2[10]), [a2_11]"+v"(A2[11]), [a2_12]"+v"(A2[12]), [a2_13]"+v"(A2[13]), [a2_14]"+v"(A2[14]),
          [a3_0]"+v"(A3[0]), [a3_1]"+v"(A3[1]), [a3_2]"+v"(A3[2]), [a3_3]"+v"(A3[3]), [a3_4]"+v"(A3[4]),
          [a3_5]"+v"(A3[5]), [a3_6]"+v"(A3[6]), [a3_7]"+v"(A3[7]), [a3_8]"+v"(A3[8]), [a3_9]"+v"(A3[9]),
          [a3_10]"+v"(A3[10]), [a3_11]"+v"(A3[11]), [a3_12]"+v"(A3[12]), [a3_13]"+v"(A3[13]), [a3_14]"+v"(A3[14]),
          [a3_15]"+v"(A3[15]), [a3_16]"+v"(A3[16]), [a3_17]"+v"(A3[17]), [a3_18]"+v"(A3[18]), [a3_19]"+v"(A3[19])
        : [ab]"v"(ab), [abm]"v"(abm), [vm]"v"(vmu)
        : "vcc", "s90", "s91", "memory",
          "v0","v1","v2","v3","v4","v5","v6","v7","v8","v9",
          "v10","v11","v12","v13","v14","v15","v16","v17","v18","v19",
          "v20");

    // ---- epilogue: triangle-weighted T + diag Im, 5-lane reduce ----
    // G symmetric at end: T = sum_{i<=j} |G_ij|^2 (gL_i gR_j + [i<j] gL_j gR_i)
    float tv = 0.0f, dv = 0.0f;
    const float gRj0 = sgR[j0], gRj1 = sgR[j1], gRj2 = sgR[j2], gRj3 = sgR[j3];
    const float gLj0 = sgL[j0], gLj1 = sgL[j1], gLj2 = sgL[j2], gLj3 = sgL[j3];
#define ACC(A, I, J, GRJ, GLJ) { \
        float mag = fmaf(A.x, A.x, A.y * A.y); \
        float w2 = ((I) <= (J)) ? fmaf(sgL[I], GRJ, ((I) < (J)) ? GLJ * sgR[I] : 0.0f) : 0.0f; \
        tv = fmaf(mag, w2, tv); \
        dv += ((I) == (J)) ? A.y : 0.0f; }
    #pragma unroll
    for (int i = 0; i < 5;  ++i) ACC(A0[i], i, j0, gRj0, gLj0)
    #pragma unroll
    for (int i = 0; i < 10; ++i) ACC(A1[i], i, j1, gRj1, gLj1)
    #pragma unroll
    for (int i = 0; i < 15; ++i) ACC(A2[i], i, j2, gRj2, gLj2)
    #pragma unroll
    for (int i = 0; i < 20; ++i) ACC(A3[i], i, j3, gRj3, gLj3)
#undef ACC

    #pragma unroll
    for (int d = 4; d >= 1; d >>= 1) {
        float t2 = __shfl(tv, lane + d, 64);
        float d2 = __shfl(dv, lane + d, 64);
        if (m + d < 5) { tv += t2; dv += d2; }
    }
    if (m == 0) {
        out[T_OFF + b * NE + e] = __log10f(fmaxf(tv, 1e-16f));
        out[D_OFF + b * NE + e] = __log10f(fmaxf(-dv, 1e-16f));
    }
}

extern "C" void kernel_launch(void* const* d_in, const int* in_sizes, int n_in,
                              void* d_out, int out_size, void* d_ws, size_t ws_size,
                              hipStream_t stream) {
    const float* tri = (const float*)d_in[0];
    const float* gL  = (const float*)d_in[1];
    const float* gR  = (const float*)d_in[2];
    float* out = (float*)d_out;
    negf_all<<<2304, 256, 0, stream>>>(tri, gL, gR, out);
}

// Round 14
// 89.571 us; speedup vs baseline: 1.0574x; 1.0574x over previous
//
#include <hip/hip_runtime.h>

// DNA transport NEGF: per (b,e) invert A = (E*I - H) + i*diag(0.5*(gL+gR)),
// DOS = -Im tr(Gr), T = sum_ij gL_i gR_j |Gr_ij|^2, plus H scatter output.
//
// R10 TRIANGULAR GJ (validated, absmax 1.95e-3): complex-symmetric no-pivot
// GJ keeps M[i][j] = +-M[j][i] -> store only rows 0..j per column. 5 lanes
// per matrix, lane m owns cols j = 5c+m; 12 matrices/wave; pivot-COLUMN
// broadcast makes updates sign-free; row k updated uniformly and fixed after.
//
// R12 LEAN ASM (validated correct): clobbers 36 -> 21 (2-deep quad window
// v0-7, p in-place v8:9, t0-t3 = v12-19, TM temp v10:11 + v20).
// R12 FAILURE: amdgpu_waves_per_eu(4) (min-only) let the allocator chase
// 8 waves/EU -> 64 arch VGPRs + massive scratch spill (FETCH 31MB, WRITE
// 84MB/dispatch). Lesson: min-waves attributes invite frugal spilling.
//
// R13: __launch_bounds__(256, 3) -> 170-VGPR cap. Live set ~145 (100 asm
// operands + 21 clobbers + addr + C overhead) fits with headroom -> no
// spill, no remat, and occupancy tier 3 waves/SIMD (waves = floor(512/v)
// admits 3 at <=170) vs R10/R11's 2 at the 256 granule.
//
// No pivoting: imag(x^* A x) > 0 for all leading blocks => pivots bounded
// below by min_i 0.5(gL_i+gR_i). Stable in fp32 (R0-R12: absmax <= 3.9e-3).

typedef float f32x2 __attribute__((ext_vector_type(2)));

#define H_N   20
#define NE    100
#define T_OFF 0
#define D_OFF 102400
#define H_OFF 204800

__device__ __forceinline__ int triIdx(int i, int j) {  // i <= j, row-major triu
    return i * H_N - ((i * (i - 1)) >> 1) + (j - i);
}

// ---------------- asm building blocks ----------------
// v0:3 / v4:7 rotating quad window; v8:9 pivot -> p (in-place); v10 den /
// v10:11 TM temp; v12:13 t0, v14:15 t1, v16:17 t2, v18:19 t3; v20 scalar.
// s[90:91] exec save.

#define WSLOT(AK, OFF) "ds_write_b64 %[abm], %[" #AK "] offset:" #OFF "\n\t"
#define WMIX(AK, OFF, MS) \
  "v_cmp_lt_u32 vcc, " #MS ", %[vm]\n\t" \
  "s_and_saveexec_b64 s[90:91], vcc\n\t" \
  "ds_write_b64 %[abm], %[" #AK "] offset:" #OFF "\n\t" \
  "s_mov_b64 exec, s[90:91]\n\t"
#define BSTB(MS) \
  "v_cmp_eq_u32 vcc, " #MS ", %[vm]\n\t" \
  "s_and_saveexec_b64 s[90:91], vcc\n\t"
#define BSTE "s_mov_b64 exec, s[90:91]\n\t"
#define BW(AK, OFF) "ds_write_b64 %[ab], %[" #AK "] offset:" #OFF "\n\t"
#define PIV(OFF) "ds_read_b64 v[8:9], %[ab] offset:" #OFF "\n\t"
#define EXR(T0, T1, OFF) "ds_read_b64 v[" #T0 ":" #T1 "], %[abm] offset:" #OFF "\n\t"
#define EX0 EXR(12,13,0)
#define EX1 EX0 EXR(14,15,40)
#define EX2 EX1 EXR(16,17,80)
#define EX3 EX2 EXR(18,19,120)
#define QISS2 \
  "ds_read_b128 v[0:3], %[ab] offset:0\n\t" \
  "ds_read_b128 v[4:7], %[ab] offset:16\n\t"
#define PCHAIN(WP) \
  "s_waitcnt lgkmcnt(" #WP ")\n\t" \
  "v_mul_f32 v10, v8, v8\n\t" \
  "v_fmac_f32 v10, v9, v9\n\t" \
  "v_rcp_f32 v10, v10\n\t" \
  "s_nop 1\n\t" \
  "v_mul_f32 v8, v8, v10\n\t" \
  "v_mul_f32 v9, -v9, v10\n\t"
#define TP(T0, T1, AK) \
  "v_pk_mul_f32 v[" #T0 ":" #T1 "], %[" #AK "], v[8:9] op_sel:[1,1] op_sel_hi:[1,0] neg_lo:[1,0]\n\t" \
  "v_pk_fma_f32 v[" #T0 ":" #T1 "], %[" #AK "], v[8:9], v[" #T0 ":" #T1 "] op_sel_hi:[0,1,1]\n\t"
#define TN(T0, T1) \
  "v_pk_mul_f32 v[10:11], v[" #T0 ":" #T1 "], v[8:9] op_sel:[1,1] op_sel_hi:[1,0] neg_hi:[1,0]\n\t" \
  "v_pk_fma_f32 v[" #T0 ":" #T1 "], v[" #T0 ":" #T1 "], v[8:9], v[10:11] op_sel_hi:[0,1,1] neg_lo:[1,0,0] neg_hi:[1,0,0]\n\t"
#define TM(T0, T1, AK, MS) \
  TN(T0, T1) \
  "v_pk_mul_f32 v[10:11], %[" #AK "], v[8:9] op_sel:[1,1] op_sel_hi:[1,0] neg_lo:[1,0]\n\t" \
  "v_pk_fma_f32 v[10:11], %[" #AK "], v[8:9], v[10:11] op_sel_hi:[0,1,1]\n\t" \
  "v_cmp_lt_u32 vcc, " #MS ", %[vm]\n\t" \
  "v_cndmask_b32 v" #T0 ", v" #T0 ", v10, vcc\n\t" \
  "v_cndmask_b32 v" #T1 ", v" #T1 ", v11, vcc\n\t" \
  "v_add_f32 v20, 1.0, v8\n\t" \
  "v_cmp_eq_u32 vcc, " #MS ", %[vm]\n\t" \
  "v_cndmask_b32 v" #T0 ", v" #T0 ", v20, vcc\n\t" \
  "v_cndmask_b32 v" #T1 ", v" #T1 ", v9, vcc\n\t"
#define WAITEX "s_waitcnt lgkmcnt(2)\n\t"
#define PSET(AK, T0, T1) \
  "v_pk_mul_f32 %[" #AK "], v[" #T0 ":" #T1 "], 1.0 op_sel_hi:[1,0]\n\t"
#define POWN(AK, T0, T1, MS) \
  "v_cmp_eq_u32 vcc, " #MS ", %[vm]\n\t" \
  "v_cndmask_b32 v" #T0 ", v" #T0 ", v8, vcc\n\t" \
  "v_cndmask_b32 v" #T1 ", v" #T1 ", v9, vcc\n\t" \
  PSET(AK, T0, T1)
#define U(A, Y0, Y1, T0, T1) \
  "v_pk_fma_f32 %[" #A "], v[" #Y0 ":" #Y1 "], v[" #T0 ":" #T1 "], %[" #A "] op_sel:[1,1,0] op_sel_hi:[1,0,1] neg_hi:[1,0,0]\n\t" \
  "v_pk_fma_f32 %[" #A "], v[" #Y0 ":" #Y1 "], v[" #T0 ":" #T1 "], %[" #A "] op_sel_hi:[0,1,1] neg_lo:[1,0,0] neg_hi:[1,0,0]\n\t"

#define BUA0 BW(a0_0,0)
#define BUA1 BUA0 BW(a0_1,8)
#define BUA2 BUA1 BW(a0_2,16)
#define BUA3 BUA2 BW(a0_3,24)
#define BUA4 BUA3 BW(a0_4,32)
#define BUB4 BW(a1_0,0) BW(a1_1,8) BW(a1_2,16) BW(a1_3,24) BW(a1_4,32)
#define BUB5 BUB4 BW(a1_5,40)
#define BUB6 BUB5 BW(a1_6,48)
#define BUB7 BUB6 BW(a1_7,56)
#define BUB8 BUB7 BW(a1_8,64)
#define BUB9 BUB8 BW(a1_9,72)
#define BUC9 BW(a2_0,0) BW(a2_1,8) BW(a2_2,16) BW(a2_3,24) BW(a2_4,32) \
             BW(a2_5,40) BW(a2_6,48) BW(a2_7,56) BW(a2_8,64) BW(a2_9,72)
#define BUC10 BUC9 BW(a2_10,80)
#define BUC11 BUC10 BW(a2_11,88)
#define BUC12 BUC11 BW(a2_12,96)
#define BUC13 BUC12 BW(a2_13,104)
#define BUC14 BUC13 BW(a2_14,112)
#define BUD14 BW(a3_0,0) BW(a3_1,8) BW(a3_2,16) BW(a3_3,24) BW(a3_4,32) \
              BW(a3_5,40) BW(a3_6,48) BW(a3_7,56) BW(a3_8,64) BW(a3_9,72) \
              BW(a3_10,80) BW(a3_11,88) BW(a3_12,96) BW(a3_13,104) BW(a3_14,112)
#define BUD15 BUD14 BW(a3_15,120)
#define BUD16 BUD15 BW(a3_16,128)
#define BUD17 BUD16 BW(a3_17,136)
#define BUD18 BUD17 BW(a3_18,144)
#define BUD19 BUD18 BW(a3_19,152)

// 50 row-updates, 2-deep rotating window, counted waits, re-issue after use
#define ALLQ \
  "s_waitcnt lgkmcnt(1)\n\t" \
  U(a3_0,0,1,18,19) U(a3_1,2,3,18,19) U(a2_0,0,1,16,17) U(a2_1,2,3,16,17) \
  U(a1_0,0,1,14,15) U(a1_1,2,3,14,15) U(a0_0,0,1,12,13) U(a0_1,2,3,12,13) \
  "ds_read_b128 v[0:3], %[ab] offset:32\n\t" \
  "s_waitcnt lgkmcnt(1)\n\t" \
  U(a3_2,4,5,18,19) U(a3_3,6,7,18,19) U(a2_2,4,5,16,17) U(a2_3,6,7,16,17) \
  U(a1_2,4,5,14,15) U(a1_3,6,7,14,15) U(a0_2,4,5,12,13) U(a0_3,6,7,12,13) \
  "ds_read_b128 v[4:7], %[ab] offset:48\n\t" \
  "s_waitcnt lgkmcnt(1)\n\t" \
  U(a3_4,0,1,18,19) U(a3_5,2,3,18,19) U(a2_4,0,1,16,17) U(a2_5,2,3,16,17) \
  U(a1_4,0,1,14,15) U(a1_5,2,3,14,15) U(a0_4,0,1,12,13) \
  "ds_read_b128 v[0:3], %[ab] offset:64\n\t" \
  "s_waitcnt lgkmcnt(1)\n\t" \
  U(a3_6,4,5,18,19) U(a3_7,6,7,18,19) U(a2_6,4,5,16,17) U(a2_7,6,7,16,17) \
  U(a1_6,4,5,14,15) U(a1_7,6,7,14,15) \
  "ds_read_b128 v[4:7], %[ab] offset:80\n\t" \
  "s_waitcnt lgkmcnt(1)\n\t" \
  U(a3_8,0,1,18,19) U(a3_9,2,3,18,19) U(a2_8,0,1,16,17) U(a2_9,2,3,16,17) \
  U(a1_8,0,1,14,15) U(a1_9,2,3,14,15) \
  "ds_read_b128 v[0:3], %[ab] offset:96\n\t" \
  "s_waitcnt lgkmcnt(1)\n\t" \
  U(a3_10,4,5,18,19) U(a3_11,6,7,18,19) U(a2_10,4,5,16,17) U(a2_11,6,7,16,17) \
  "ds_read_b128 v[4:7], %[ab] offset:112\n\t" \
  "s_waitcnt lgkmcnt(1)\n\t" \
  U(a3_12,0,1,18,19) U(a3_13,2,3,18,19) U(a2_12,0,1,16,17) U(a2_13,2,3,16,17) \
  "ds_read_b128 v[0:3], %[ab] offset:128\n\t" \
  "s_waitcnt lgkmcnt(1)\n\t" \
  U(a3_14,4,5,18,19) U(a3_15,6,7,18,19) U(a2_14,4,5,16,17) \
  "ds_read_b128 v[4:7], %[ab] offset:144\n\t" \
  "s_waitcnt lgkmcnt(1)\n\t" \
  U(a3_16,0,1,18,19) U(a3_17,2,3,18,19) \
  "s_waitcnt lgkmcnt(0)\n\t" \
  U(a3_18,4,5,18,19) U(a3_19,6,7,18,19)

#define S0  WSLOT(a1_0,40) WSLOT(a2_0,80) WSLOT(a3_0,120) WMIX(a0_0,0,0) BSTB(0) BUA0 BSTE PIV(0)  EX0 QISS2 PCHAIN(3) TP(14,15,a1_0) TP(16,17,a2_0) TP(18,19,a3_0) WAITEX TM(12,13,a0_0,0) ALLQ PSET(a1_0,14,15) PSET(a2_0,16,17) PSET(a3_0,18,19) POWN(a0_0,12,13,0)
#define S1  WSLOT(a1_1,40) WSLOT(a2_1,80) WSLOT(a3_1,120) WMIX(a0_1,0,1) BSTB(1) BUA1 BSTE PIV(8)  EX0 QISS2 PCHAIN(3) TP(14,15,a1_1) TP(16,17,a2_1) TP(18,19,a3_1) WAITEX TM(12,13,a0_1,1) ALLQ PSET(a1_1,14,15) PSET(a2_1,16,17) PSET(a3_1,18,19) POWN(a0_1,12,13,1)
#define S2  WSLOT(a1_2,40) WSLOT(a2_2,80) WSLOT(a3_2,120) WMIX(a0_2,0,2) BSTB(2) BUA2 BSTE PIV(16) EX0 QISS2 PCHAIN(3) TP(14,15,a1_2) TP(16,17,a2_2) TP(18,19,a3_2) WAITEX TM(12,13,a0_2,2) ALLQ PSET(a1_2,14,15) PSET(a2_2,16,17) PSET(a3_2,18,19) POWN(a0_2,12,13,2)
#define S3  WSLOT(a1_3,40) WSLOT(a2_3,80) WSLOT(a3_3,120) WMIX(a0_3,0,3) BSTB(3) BUA3 BSTE PIV(24) EX0 QISS2 PCHAIN(3) TP(14,15,a1_3) TP(16,17,a2_3) TP(18,19,a3_3) WAITEX TM(12,13,a0_3,3) ALLQ PSET(a1_3,14,15) PSET(a2_3,16,17) PSET(a3_3,18,19) POWN(a0_3,12,13,3)
#define S4  WSLOT(a1_4,40) WSLOT(a2_4,80) WSLOT(a3_4,120)                BSTB(4) BUA4 BSTE PIV(32) EX0 QISS2 PCHAIN(3) TP(14,15,a1_4) TP(16,17,a2_4) TP(18,19,a3_4) WAITEX TM(12,13,a0_4,4) ALLQ PSET(a1_4,14,15) PSET(a2_4,16,17) PSET(a3_4,18,19) POWN(a0_4,12,13,4)
#define S5  WSLOT(a2_5,80) WSLOT(a3_5,120) WMIX(a1_5,40,0) BSTB(0) BUB5 BSTE PIV(40) EX1 QISS2 PCHAIN(4) TP(16,17,a2_5) TP(18,19,a3_5) WAITEX TN(12,13) TM(14,15,a1_5,0) ALLQ PSET(a2_5,16,17) PSET(a3_5,18,19) POWN(a1_5,14,15,0)
#define S6  WSLOT(a2_6,80) WSLOT(a3_6,120) WMIX(a1_6,40,1) BSTB(1) BUB6 BSTE PIV(48) EX1 QISS2 PCHAIN(4) TP(16,17,a2_6) TP(18,19,a3_6) WAITEX TN(12,13) TM(14,15,a1_6,1) ALLQ PSET(a2_6,16,17) PSET(a3_6,18,19) POWN(a1_6,14,15,1)
#define S7  WSLOT(a2_7,80) WSLOT(a3_7,120) WMIX(a1_7,40,2) BSTB(2) BUB7 BSTE PIV(56) EX1 QISS2 PCHAIN(4) TP(16,17,a2_7) TP(18,19,a3_7) WAITEX TN(12,13) TM(14,15,a1_7,2) ALLQ PSET(a2_7,16,17) PSET(a3_7,18,19) POWN(a1_7,14,15,2)
#define S8  WSLOT(a2_8,80) WSLOT(a3_8,120) WMIX(a1_8,40,3) BSTB(3) BUB8 BSTE PIV(64) EX1 QISS2 PCHAIN(4) TP(16,17,a2_8) TP(18,19,a3_8) WAITEX TN(12,13) TM(14,15,a1_8,3) ALLQ PSET(a2_8,16,17) PSET(a3_8,18,19) POWN(a1_8,14,15,3)
#define S9  WSLOT(a2_9,80) WSLOT(a3_9,120)                 BSTB(4) BUB9 BSTE PIV(72) EX1 QISS2 PCHAIN(4) TP(16,17,a2_9) TP(18,19,a3_9) WAITEX TN(12,13) TM(14,15,a1_9,4) ALLQ PSET(a2_9,16,17) PSET(a3_9,18,19) POWN(a1_9,14,15,4)
#define S10 WSLOT(a3_10,120) WMIX(a2_10,80,0) BSTB(0) BUC10 BSTE PIV(80)  EX2 QISS2 PCHAIN(5) TP(18,19,a3_10) WAITEX TN(12,13) TN(14,15) TM(16,17,a2_10,0) ALLQ PSET(a3_10,18,19) POWN(a2_10,16,17,0)
#define S11 WSLOT(a3_11,120) WMIX(a2_11,80,1) BSTB(1) BUC11 BSTE PIV(88)  EX2 QISS2 PCHAIN(5) TP(18,19,a3_11) WAITEX TN(12,13) TN(14,15) TM(16,17,a2_11,1) ALLQ PSET(a3_11,18,19) POWN(a2_11,16,17,1)
#define S12 WSLOT(a3_12,120) WMIX(a2_12,80,2) BSTB(2) BUC12 BSTE PIV(96)  EX2 QISS2 PCHAIN(5) TP(18,19,a3_12) WAITEX TN(12,13) TN(14,15) TM(16,17,a2_12,2) ALLQ PSET(a3_12,18,19) POWN(a2_12,16,17,2)
#define S13 WSLOT(a3_13,120) WMIX(a2_13,80,3) BSTB(3) BUC13 BSTE PIV(104) EX2 QISS2 PCHAIN(5) TP(18,19,a3_13) WAITEX TN(12,13) TN(14,15) TM(16,17,a2_13,3) ALLQ PSET(a3_13,18,19) POWN(a2_13,16,17,3)
#define S14 WSLOT(a3_14,120)                  BSTB(4) BUC14 BSTE PIV(112) EX2 QISS2 PCHAIN(5) TP(18,19,a3_14) WAITEX TN(12,13) TN(14,15) TM(16,17,a2_14,4) ALLQ PSET(a3_14,18,19) POWN(a2_14,16,17,4)
#define S15 WMIX(a3_15,120,0) BSTB(0) BUD15 BSTE PIV(120) EX3 QISS2 PCHAIN(6) WAITEX TN(12,13) TN(14,15) TN(16,17) TM(18,19,a3_15,0) ALLQ POWN(a3_15,18,19,0)
#define S16 WMIX(a3_16,120,1) BSTB(1) BUD16 BSTE PIV(128) EX3 QISS2 PCHAIN(6) WAITEX TN(12,13) TN(14,15) TN(16,17) TM(18,19,a3_16,1) ALLQ POWN(a3_16,18,19,1)
#define S17 WMIX(a3_17,120,2) BSTB(2) BUD17 BSTE PIV(136) EX3 QISS2 PCHAIN(6) WAITEX TN(12,13) TN(14,15) TN(16,17) TM(18,19,a3_17,2) ALLQ POWN(a3_17,18,19,2)
#define S18 WMIX(a3_18,120,3) BSTB(3) BUD18 BSTE PIV(144) EX3 QISS2 PCHAIN(6) WAITEX TN(12,13) TN(14,15) TN(16,17) TM(18,19,a3_18,3) ALLQ POWN(a3_18,18,19,3)
#define S19                   BSTB(4) BUD19 BSTE PIV(152) EX3 QISS2 PCHAIN(6) WAITEX TN(12,13) TN(14,15) TN(16,17) TM(18,19,a3_19,4) ALLQ POWN(a3_19,18,19,4)

__global__ __launch_bounds__(256, 3)
void negf_all(const float* __restrict__ tri,
              const float* __restrict__ GL,
              const float* __restrict__ GR,
              float* __restrict__ out)
{
    // 4 independent waves/block, each with a private 1024-float LDS slice:
    // [0,400) Hcm col-major | [400,420) sgL | [420,440) sgR | [448,976) stage
    __shared__ __align__(16) float lds[4][1024];

    const int tid  = threadIdx.x;
    const int wid  = tid >> 6;
    const int lane = tid & 63;
    const int w    = blockIdx.x * 4 + wid;     // wave unit: (b, chunk)
    const int b    = w / 9;
    const int chunk = w - b * 9;

    float* const Hcm   = &lds[wid][0];
    float* const sgL   = &lds[wid][400];
    float* const sgR   = &lds[wid][420];
    float* const stage = &lds[wid][448];

    // ---- per-wave staging of H (col-major) + gammas ----
    const float* triB = tri + b * 210;
    for (int u = lane; u < 400; u += 64) {
        int c = u / 20, r = u - c * 20;
        int lo = r < c ? r : c;
        int hi = r < c ? c : r;
        Hcm[u] = triB[triIdx(lo, hi)];
    }
    if (lane < H_N) { sgL[lane] = GL[b * H_N + lane]; sgR[lane] = GR[b * H_N + lane]; }
    asm volatile("s_waitcnt lgkmcnt(0)" ::: "memory");   // wave-coherent LDS

    // ---- H output (row-major, exact copy); one wave per b ----
    if (chunk == 0) {
        for (int u = lane; u < 400; u += 64) {
            int r = u / 20, c = u - r * 20;
            out[H_OFF + b * 400 + u] = Hcm[c * 20 + r];
        }
    }

    const int sgw = lane / 5;                  // 0..11 active, 12 idle (60-63)
    const int m   = lane - sgw * 5;            // 0..4
    const int e   = chunk * 12 + sgw;
    if (sgw >= 12 || e >= NE) return;

    const int j0 = m, j1 = 5 + m, j2 = 10 + m, j3 = 15 + m;
    const float gam0 = 0.5f * (sgL[j0] + sgR[j0]);
    const float gam1 = 0.5f * (sgL[j1] + sgR[j1]);
    const float gam2 = 0.5f * (sgL[j2] + sgR[j2]);
    const float gam3 = 0.5f * (sgL[j3] + sgR[j3]);
    const float E = fmaf((float)e, 6.0f / 99.0f, -3.0f);

    // ---- init triangle columns (invalid rows -> 0, kept finite) ----
    f32x2 A0[5], A1[10], A2[15], A3[20];
#define MK(DST, I, J, G) { \
        float h = Hcm[(J) * 20 + (I)]; \
        bool vl = (I) <= (J); bool dg = (I) == (J); \
        DST.x = vl ? (dg ? (E - h) : -h) : 0.0f; \
        DST.y = vl ? (dg ? (G) : 0.0f) : 0.0f; }
    #pragma unroll
    for (int i = 0; i < 5;  ++i) MK(A0[i], i, j0, gam0)
    #pragma unroll
    for (int i = 0; i < 10; ++i) MK(A1[i], i, j1, gam1)
    #pragma unroll
    for (int i = 0; i < 15; ++i) MK(A2[i], i, j2, gam2)
    #pragma unroll
    for (int i = 0; i < 20; ++i) MK(A3[i], i, j3, gam3)
#undef MK

    const unsigned ab  = (unsigned)(size_t)&stage[sgw * 44];
    const unsigned abm = ab + 8u * (unsigned)m;
    const unsigned vmu = (unsigned)m;

    asm volatile(
        "s_waitcnt lgkmcnt(0)\n\t"
        S0 S1 S2 S3 S4 S5 S6 S7 S8 S9
        S10 S11 S12 S13 S14 S15 S16 S17 S18 S19
        : [a0_0]"+v"(A0[0]), [a0_1]"+v"(A0[1]), [a0_2]"+v"(A0[2]), [a0_3]"+v"(A0[3]), [a0_4]"+v"(A0[4]),
          [a1_0]"+v"(A1[0]), [a1_1]"+v"(A1[1]), [a1_2]"+v"(A1[2]), [a1_3]"+v"(A1[3]), [a1_4]"+v"(A1[4]),
          [a1_5]"+v"(A1[5]), [a1_6]"+v"(A1[6]), [a1_7]"+v"(A1[7]), [a1_8]"+v"(A1[8]), [a1_9]"+v"(A1[9]),
          [a2_0]"+v"(A2[0]), [a2_1]"+v"(A2[1]), [a2_2]"+v"(A2[2]), [a2_3]"+v"(A2[3]), [a2_4]"+v"(A2[4]),
          [a2_5]"+v"(A2[5]), [a2_6]"+v"(A2[6]), [a2_7]"+v"(A2[7]), [a2_8]"+v"(A2[8]), [a2_9]"+v"(A2[9]),
          [a2_10]"+v"(A2[10]), [a2_11]"+v"(A2[11]), [a2_12]"+v"(A2[12]), [a2_13]"+v"(A2[13]), [a2_14]"+v"(A2[14]),
          [a3_0]"+v"(A3[0]), [a3_1]"+v"(A3[1]), [a3_2]"+v"(A3[2]), [a3_3]"+v"(A3[3]), [a3_4]"+v"(A3[4]),
          [a3_5]"+v"(A3[5]), [a3_6]"+v"(A3[6]), [a3_7]"+v"(A3[7]), [a3_8]"+v"(A3[8]), [a3_9]"+v"(A3[9]),
          [a3_10]"+v"(A3[10]), [a3_11]"+v"(A3[11]), [a3_12]"+v"(A3[12]), [a3_13]"+v"(A3[13]), [a3_14]"+v"(A3[14]),
          [a3_15]"+v"(A3[15]), [a3_16]"+v"(A3[16]), [a3_17]"+v"(A3[17]), [a3_18]"+v"(A3[18]), [a3_19]"+v"(A3[19])
        : [ab]"v"(ab), [abm]"v"(abm), [vm]"v"(vmu)
        : "vcc", "s90", "s91", "memory",
          "v0","v1","v2","v3","v4","v5","v6","v7","v8","v9",
          "v10","v11","v12","v13","v14","v15","v16","v17","v18","v19",
          "v20");

    // ---- epilogue: triangle-weighted T + diag Im, 5-lane reduce ----
    // G symmetric at end: T = sum_{i<=j} |G_ij|^2 (gL_i gR_j + [i<j] gL_j gR_i)
    float tv = 0.0f, dv = 0.0f;
    const float gRj0 = sgR[j0], gRj1 = sgR[j1], gRj2 = sgR[j2], gRj3 = sgR[j3];
    const float gLj0 = sgL[j0], gLj1 = sgL[j1], gLj2 = sgL[j2], gLj3 = sgL[j3];
#define ACC(A, I, J, GRJ, GLJ) { \
        float mag = fmaf(A.x, A.x, A.y * A.y); \
        float w2 = ((I) <= (J)) ? fmaf(sgL[I], GRJ, ((I) < (J)) ? GLJ * sgR[I] : 0.0f) : 0.0f; \
        tv = fmaf(mag, w2, tv); \
        dv += ((I) == (J)) ? A.y : 0.0f; }
    #pragma unroll
    for (int i = 0; i < 5;  ++i) ACC(A0[i], i, j0, gRj0, gLj0)
    #pragma unroll
    for (int i = 0; i < 10; ++i) ACC(A1[i], i, j1, gRj1, gLj1)
    #pragma unroll
    for (int i = 0; i < 15; ++i) ACC(A2[i], i, j2, gRj2, gLj2)
    #pragma unroll
    for (int i = 0; i < 20; ++i) ACC(A3[i], i, j3, gRj3, gLj3)
#undef ACC

    #pragma unroll
    for (int d = 4; d >= 1; d >>= 1) {
        float t2 = __shfl(tv, lane + d, 64);
        float d2 = __shfl(dv, lane + d, 64);
        if (m + d < 5) { tv += t2; dv += d2; }
    }
    if (m == 0) {
        out[T_OFF + b * NE + e] = __log10f(fmaxf(tv, 1e-16f));
        out[D_OFF + b * NE + e] = __log10f(fmaxf(-dv, 1e-16f));
    }
}

extern "C" void kernel_launch(void* const* d_in, const int* in_sizes, int n_in,
                              void* d_out, int out_size, void* d_ws, size_t ws_size,
                              hipStream_t stream) {
    const float* tri = (const float*)d_in[0];
    const float* gL  = (const float*)d_in[1];
    const float* gR  = (const float*)d_in[2];
    float* out = (float*)d_out;
    negf_all<<<2304, 256, 0, stream>>>(tri, gL, gR, out);
}

// Round 15
// 87.546 us; speedup vs baseline: 1.0818x; 1.0231x over previous
//
#include <hip/hip_runtime.h>

// DNA transport NEGF: per (b,e) invert A = (E*I - H) + i*diag(0.5*(gL+gR)),
// DOS = -Im tr(Gr), T = sum_ij gL_i gR_j |Gr_ij|^2, plus H scatter output.
//
// R10 TRIANGULAR GJ (validated): complex-symmetric no-pivot GJ keeps
// M[i][j]=+-M[j][i] -> store rows 0..j per column. 5 lanes/matrix, lane m
// owns cols 5c+m; 12 matrices/wave; pivot-column broadcast, sign-free
// updates; row k updated uniformly, fixed after. Lean asm (R12-validated):
// 21 clobbers, 2-deep quad window, counted lgkmcnt.
//
// R13 ANALYSIS: VALUBusy*dur = 64.4us == FP32-pipe model (v_pk_fma_f32 = 8
// cyc: 256 FMA-lanes at 32 FMA/cyc/SIMD; 100 pk/step * 20 * 9 waves/SIMD).
// Strictly FLOP-rate-bound for 64us + ~41us unhidden stall at 2 waves/SIMD.
// Occupancy stuck: reported VGPR=80 < 124 asm-required => rest in AGPRs
// (unified file); occupancy charged on TOTAL, inflated by C-side values
// kept live across the asm.
//
// R14 LIVENESS HYGIENE: post-asm, launder threadIdx through opaque asm and
// recompute ALL indices/pointers from scratch (no CSE with pre-asm values);
// reload gammas from LDS. Live-across = the 100 operands only -> total
// ~124-150 <= 170 tier -> 3 waves/SIMD.
//
// No pivoting: imag(x^* A x) > 0 for all leading blocks => pivots bounded
// below. Stable in fp32 (R0-R13: absmax <= 3.9e-3).

typedef float f32x2 __attribute__((ext_vector_type(2)));

#define H_N   20
#define NE    100
#define T_OFF 0
#define D_OFF 102400
#define H_OFF 204800

__device__ __forceinline__ int triIdx(int i, int j) {  // i <= j, row-major triu
    return i * H_N - ((i * (i - 1)) >> 1) + (j - i);
}

// ---------------- asm building blocks (R12/R13, validated) ----------------
// v0:3 / v4:7 rotating quad window; v8:9 pivot -> p (in-place); v10 den /
// v10:11 TM temp; v12:13 t0, v14:15 t1, v16:17 t2, v18:19 t3; v20 scalar.
// s[90:91] exec save.

#define WSLOT(AK, OFF) "ds_write_b64 %[abm], %[" #AK "] offset:" #OFF "\n\t"
#define WMIX(AK, OFF, MS) \
  "v_cmp_lt_u32 vcc, " #MS ", %[vm]\n\t" \
  "s_and_saveexec_b64 s[90:91], vcc\n\t" \
  "ds_write_b64 %[abm], %[" #AK "] offset:" #OFF "\n\t" \
  "s_mov_b64 exec, s[90:91]\n\t"
#define BSTB(MS) \
  "v_cmp_eq_u32 vcc, " #MS ", %[vm]\n\t" \
  "s_and_saveexec_b64 s[90:91], vcc\n\t"
#define BSTE "s_mov_b64 exec, s[90:91]\n\t"
#define BW(AK, OFF) "ds_write_b64 %[ab], %[" #AK "] offset:" #OFF "\n\t"
#define PIV(OFF) "ds_read_b64 v[8:9], %[ab] offset:" #OFF "\n\t"
#define EXR(T0, T1, OFF) "ds_read_b64 v[" #T0 ":" #T1 "], %[abm] offset:" #OFF "\n\t"
#define EX0 EXR(12,13,0)
#define EX1 EX0 EXR(14,15,40)
#define EX2 EX1 EXR(16,17,80)
#define EX3 EX2 EXR(18,19,120)
#define QISS2 \
  "ds_read_b128 v[0:3], %[ab] offset:0\n\t" \
  "ds_read_b128 v[4:7], %[ab] offset:16\n\t"
#define PCHAIN(WP) \
  "s_waitcnt lgkmcnt(" #WP ")\n\t" \
  "v_mul_f32 v10, v8, v8\n\t" \
  "v_fmac_f32 v10, v9, v9\n\t" \
  "v_rcp_f32 v10, v10\n\t" \
  "s_nop 1\n\t" \
  "v_mul_f32 v8, v8, v10\n\t" \
  "v_mul_f32 v9, -v9, v10\n\t"
#define TP(T0, T1, AK) \
  "v_pk_mul_f32 v[" #T0 ":" #T1 "], %[" #AK "], v[8:9] op_sel:[1,1] op_sel_hi:[1,0] neg_lo:[1,0]\n\t" \
  "v_pk_fma_f32 v[" #T0 ":" #T1 "], %[" #AK "], v[8:9], v[" #T0 ":" #T1 "] op_sel_hi:[0,1,1]\n\t"
#define TN(T0, T1) \
  "v_pk_mul_f32 v[10:11], v[" #T0 ":" #T1 "], v[8:9] op_sel:[1,1] op_sel_hi:[1,0] neg_hi:[1,0]\n\t" \
  "v_pk_fma_f32 v[" #T0 ":" #T1 "], v[" #T0 ":" #T1 "], v[8:9], v[10:11] op_sel_hi:[0,1,1] neg_lo:[1,0,0] neg_hi:[1,0,0]\n\t"
#define TM(T0, T1, AK, MS) \
  TN(T0, T1) \
  "v_pk_mul_f32 v[10:11], %[" #AK "], v[8:9] op_sel:[1,1] op_sel_hi:[1,0] neg_lo:[1,0]\n\t" \
  "v_pk_fma_f32 v[10:11], %[" #AK "], v[8:9], v[10:11] op_sel_hi:[0,1,1]\n\t" \
  "v_cmp_lt_u32 vcc, " #MS ", %[vm]\n\t" \
  "v_cndmask_b32 v" #T0 ", v" #T0 ", v10, vcc\n\t" \
  "v_cndmask_b32 v" #T1 ", v" #T1 ", v11, vcc\n\t" \
  "v_add_f32 v20, 1.0, v8\n\t" \
  "v_cmp_eq_u32 vcc, " #MS ", %[vm]\n\t" \
  "v_cndmask_b32 v" #T0 ", v" #T0 ", v20, vcc\n\t" \
  "v_cndmask_b32 v" #T1 ", v" #T1 ", v9, vcc\n\t"
#define WAITEX "s_waitcnt lgkmcnt(2)\n\t"
#define PSET(AK, T0, T1) \
  "v_pk_mul_f32 %[" #AK "], v[" #T0 ":" #T1 "], 1.0 op_sel_hi:[1,0]\n\t"
#define POWN(AK, T0, T1, MS) \
  "v_cmp_eq_u32 vcc, " #MS ", %[vm]\n\t" \
  "v_cndmask_b32 v" #T0 ", v" #T0 ", v8, vcc\n\t" \
  "v_cndmask_b32 v" #T1 ", v" #T1 ", v9, vcc\n\t" \
  PSET(AK, T0, T1)
#define U(A, Y0, Y1, T0, T1) \
  "v_pk_fma_f32 %[" #A "], v[" #Y0 ":" #Y1 "], v[" #T0 ":" #T1 "], %[" #A "] op_sel:[1,1,0] op_sel_hi:[1,0,1] neg_hi:[1,0,0]\n\t" \
  "v_pk_fma_f32 %[" #A "], v[" #Y0 ":" #Y1 "], v[" #T0 ":" #T1 "], %[" #A "] op_sel_hi:[0,1,1] neg_lo:[1,0,0] neg_hi:[1,0,0]\n\t"

#define BUA0 BW(a0_0,0)
#define BUA1 BUA0 BW(a0_1,8)
#define BUA2 BUA1 BW(a0_2,16)
#define BUA3 BUA2 BW(a0_3,24)
#define BUA4 BUA3 BW(a0_4,32)
#define BUB4 BW(a1_0,0) BW(a1_1,8) BW(a1_2,16) BW(a1_3,24) BW(a1_4,32)
#define BUB5 BUB4 BW(a1_5,40)
#define BUB6 BUB5 BW(a1_6,48)
#define BUB7 BUB6 BW(a1_7,56)
#define BUB8 BUB7 BW(a1_8,64)
#define BUB9 BUB8 BW(a1_9,72)
#define BUC9 BW(a2_0,0) BW(a2_1,8) BW(a2_2,16) BW(a2_3,24) BW(a2_4,32) \
             BW(a2_5,40) BW(a2_6,48) BW(a2_7,56) BW(a2_8,64) BW(a2_9,72)
#define BUC10 BUC9 BW(a2_10,80)
#define BUC11 BUC10 BW(a2_11,88)
#define BUC12 BUC11 BW(a2_12,96)
#define BUC13 BUC12 BW(a2_13,104)
#define BUC14 BUC13 BW(a2_14,112)
#define BUD14 BW(a3_0,0) BW(a3_1,8) BW(a3_2,16) BW(a3_3,24) BW(a3_4,32) \
              BW(a3_5,40) BW(a3_6,48) BW(a3_7,56) BW(a3_8,64) BW(a3_9,72) \
              BW(a3_10,80) BW(a3_11,88) BW(a3_12,96) BW(a3_13,104) BW(a3_14,112)
#define BUD15 BUD14 BW(a3_15,120)
#define BUD16 BUD15 BW(a3_16,128)
#define BUD17 BUD16 BW(a3_17,136)
#define BUD18 BUD17 BW(a3_18,144)
#define BUD19 BUD18 BW(a3_19,152)

// 50 row-updates, 2-deep rotating window, counted waits, re-issue after use
#define ALLQ \
  "s_waitcnt lgkmcnt(1)\n\t" \
  U(a3_0,0,1,18,19) U(a3_1,2,3,18,19) U(a2_0,0,1,16,17) U(a2_1,2,3,16,17) \
  U(a1_0,0,1,14,15) U(a1_1,2,3,14,15) U(a0_0,0,1,12,13) U(a0_1,2,3,12,13) \
  "ds_read_b128 v[0:3], %[ab] offset:32\n\t" \
  "s_waitcnt lgkmcnt(1)\n\t" \
  U(a3_2,4,5,18,19) U(a3_3,6,7,18,19) U(a2_2,4,5,16,17) U(a2_3,6,7,16,17) \
  U(a1_2,4,5,14,15) U(a1_3,6,7,14,15) U(a0_2,4,5,12,13) U(a0_3,6,7,12,13) \
  "ds_read_b128 v[4:7], %[ab] offset:48\n\t" \
  "s_waitcnt lgkmcnt(1)\n\t" \
  U(a3_4,0,1,18,19) U(a3_5,2,3,18,19) U(a2_4,0,1,16,17) U(a2_5,2,3,16,17) \
  U(a1_4,0,1,14,15) U(a1_5,2,3,14,15) U(a0_4,0,1,12,13) \
  "ds_read_b128 v[0:3], %[ab] offset:64\n\t" \
  "s_waitcnt lgkmcnt(1)\n\t" \
  U(a3_6,4,5,18,19) U(a3_7,6,7,18,19) U(a2_6,4,5,16,17) U(a2_7,6,7,16,17) \
  U(a1_6,4,5,14,15) U(a1_7,6,7,14,15) \
  "ds_read_b128 v[4:7], %[ab] offset:80\n\t" \
  "s_waitcnt lgkmcnt(1)\n\t" \
  U(a3_8,0,1,18,19) U(a3_9,2,3,18,19) U(a2_8,0,1,16,17) U(a2_9,2,3,16,17) \
  U(a1_8,0,1,14,15) U(a1_9,2,3,14,15) \
  "ds_read_b128 v[0:3], %[ab] offset:96\n\t" \
  "s_waitcnt lgkmcnt(1)\n\t" \
  U(a3_10,4,5,18,19) U(a3_11,6,7,18,19) U(a2_10,4,5,16,17) U(a2_11,6,7,16,17) \
  "ds_read_b128 v[4:7], %[ab] offset:112\n\t" \
  "s_waitcnt lgkmcnt(1)\n\t" \
  U(a3_12,0,1,18,19) U(a3_13,2,3,18,19) U(a2_12,0,1,16,17) U(a2_13,2,3,16,17) \
  "ds_read_b128 v[0:3], %[ab] offset:128\n\t" \
  "s_waitcnt lgkmcnt(1)\n\t" \
  U(a3_14,4,5,18,19) U(a3_15,6,7,18,19) U(a2_14,4,5,16,17) \
  "ds_read_b128 v[4:7], %[ab] offset:144\n\t" \
  "s_waitcnt lgkmcnt(1)\n\t" \
  U(a3_16,0,1,18,19) U(a3_17,2,3,18,19) \
  "s_waitcnt lgkmcnt(0)\n\t" \
  U(a3_18,4,5,18,19) U(a3_19,6,7,18,19)

#define S0  WSLOT(a1_0,40) WSLOT(a2_0,80) WSLOT(a3_0,120) WMIX(a0_0,0,0) BSTB(0) BUA0 BSTE PIV(0)  EX0 QISS2 PCHAIN(3) TP(14,15,a1_0) TP(16,17,a2_0) TP(18,19,a3_0) WAITEX TM(12,13,a0_0,0) ALLQ PSET(a1_0,14,15) PSET(a2_0,16,17) PSET(a3_0,18,19) POWN(a0_0,12,13,0)
#define S1  WSLOT(a1_1,40) WSLOT(a2_1,80) WSLOT(a3_1,120) WMIX(a0_1,0,1) BSTB(1) BUA1 BSTE PIV(8)  EX0 QISS2 PCHAIN(3) TP(14,15,a1_1) TP(16,17,a2_1) TP(18,19,a3_1) WAITEX TM(12,13,a0_1,1) ALLQ PSET(a1_1,14,15) PSET(a2_1,16,17) PSET(a3_1,18,19) POWN(a0_1,12,13,1)
#define S2  WSLOT(a1_2,40) WSLOT(a2_2,80) WSLOT(a3_2,120) WMIX(a0_2,0,2) BSTB(2) BUA2 BSTE PIV(16) EX0 QISS2 PCHAIN(3) TP(14,15,a1_2) TP(16,17,a2_2) TP(18,19,a3_2) WAITEX TM(12,13,a0_2,2) ALLQ PSET(a1_2,14,15) PSET(a2_2,16,17) PSET(a3_2,18,19) POWN(a0_2,12,13,2)
#define S3  WSLOT(a1_3,40) WSLOT(a2_3,80) WSLOT(a3_3,120) WMIX(a0_3,0,3) BSTB(3) BUA3 BSTE PIV(24) EX0 QISS2 PCHAIN(3) TP(14,15,a1_3) TP(16,17,a2_3) TP(18,19,a3_3) WAITEX TM(12,13,a0_3,3) ALLQ PSET(a1_3,14,15) PSET(a2_3,16,17) PSET(a3_3,18,19) POWN(a0_3,12,13,3)
#define S4  WSLOT(a1_4,40) WSLOT(a2_4,80) WSLOT(a3_4,120)                BSTB(4) BUA4 BSTE PIV(32) EX0 QISS2 PCHAIN(3) TP(14,15,a1_4) TP(16,17,a2_4) TP(18,19,a3_4) WAITEX TM(12,13,a0_4,4) ALLQ PSET(a1_4,14,15) PSET(a2_4,16,17) PSET(a3_4,18,19) POWN(a0_4,12,13,4)
#define S5  WSLOT(a2_5,80) WSLOT(a3_5,120) WMIX(a1_5,40,0) BSTB(0) BUB5 BSTE PIV(40) EX1 QISS2 PCHAIN(4) TP(16,17,a2_5) TP(18,19,a3_5) WAITEX TN(12,13) TM(14,15,a1_5,0) ALLQ PSET(a2_5,16,17) PSET(a3_5,18,19) POWN(a1_5,14,15,0)
#define S6  WSLOT(a2_6,80) WSLOT(a3_6,120) WMIX(a1_6,40,1) BSTB(1) BUB6 BSTE PIV(48) EX1 QISS2 PCHAIN(4) TP(16,17,a2_6) TP(18,19,a3_6) WAITEX TN(12,13) TM(14,15,a1_6,1) ALLQ PSET(a2_6,16,17) PSET(a3_6,18,19) POWN(a1_6,14,15,1)
#define S7  WSLOT(a2_7,80) WSLOT(a3_7,120) WMIX(a1_7,40,2) BSTB(2) BUB7 BSTE PIV(56) EX1 QISS2 PCHAIN(4) TP(16,17,a2_7) TP(18,19,a3_7) WAITEX TN(12,13) TM(14,15,a1_7,2) ALLQ PSET(a2_7,16,17) PSET(a3_7,18,19) POWN(a1_7,14,15,2)
#define S8  WSLOT(a2_8,80) WSLOT(a3_8,120) WMIX(a1_8,40,3) BSTB(3) BUB8 BSTE PIV(64) EX1 QISS2 PCHAIN(4) TP(16,17,a2_8) TP(18,19,a3_8) WAITEX TN(12,13) TM(14,15,a1_8,3) ALLQ PSET(a2_8,16,17) PSET(a3_8,18,19) POWN(a1_8,14,15,3)
#define S9  WSLOT(a2_9,80) WSLOT(a3_9,120)                 BSTB(4) BUB9 BSTE PIV(72) EX1 QISS2 PCHAIN(4) TP(16,17,a2_9) TP(18,19,a3_9) WAITEX TN(12,13) TM(14,15,a1_9,4) ALLQ PSET(a2_9,16,17) PSET(a3_9,18,19) POWN(a1_9,14,15,4)
#define S10 WSLOT(a3_10,120) WMIX(a2_10,80,0) BSTB(0) BUC10 BSTE PIV(80)  EX2 QISS2 PCHAIN(5) TP(18,19,a3_10) WAITEX TN(12,13) TN(14,15) TM(16,17,a2_10,0) ALLQ PSET(a3_10,18,19) POWN(a2_10,16,17,0)
#define S11 WSLOT(a3_11,120) WMIX(a2_11,80,1) BSTB(1) BUC11 BSTE PIV(88)  EX2 QISS2 PCHAIN(5) TP(18,19,a3_11) WAITEX TN(12,13) TN(14,15) TM(16,17,a2_11,1) ALLQ PSET(a3_11,18,19) POWN(a2_11,16,17,1)
#define S12 WSLOT(a3_12,120) WMIX(a2_12,80,2) BSTB(2) BUC12 BSTE PIV(96)  EX2 QISS2 PCHAIN(5) TP(18,19,a3_12) WAITEX TN(12,13) TN(14,15) TM(16,17,a2_12,2) ALLQ PSET(a3_12,18,19) POWN(a2_12,16,17,2)
#define S13 WSLOT(a3_13,120) WMIX(a2_13,80,3) BSTB(3) BUC13 BSTE PIV(104) EX2 QISS2 PCHAIN(5) TP(18,19,a3_13) WAITEX TN(12,13) TN(14,15) TM(16,17,a2_13,3) ALLQ PSET(a3_13,18,19) POWN(a2_13,16,17,3)
#define S14 WSLOT(a3_14,120)                  BSTB(4) BUC14 BSTE PIV(112) EX2 QISS2 PCHAIN(5) TP(18,19,a3_14) WAITEX TN(12,13) TN(14,15) TM(16,17,a2_14,4) ALLQ PSET(a3_14,18,19) POWN(a2_14,16,17,4)
#define S15 WMIX(a3_15,120,0) BSTB(0) BUD15 BSTE PIV(120) EX3 QISS2 PCHAIN(6) WAITEX TN(12,13) TN(14,15) TN(16,17) TM(18,19,a3_15,0) ALLQ POWN(a3_15,18,19,0)
#define S16 WMIX(a3_16,120,1) BSTB(1) BUD16 BSTE PIV(128) EX3 QISS2 PCHAIN(6) WAITEX TN(12,13) TN(14,15) TN(16,17) TM(18,19,a3_16,1) ALLQ POWN(a3_16,18,19,1)
#define S17 WMIX(a3_17,120,2) BSTB(2) BUD17 BSTE PIV(136) EX3 QISS2 PCHAIN(6) WAITEX TN(12,13) TN(14,15) TN(16,17) TM(18,19,a3_17,2) ALLQ POWN(a3_17,18,19,2)
#define S18 WMIX(a3_18,120,3) BSTB(3) BUD18 BSTE PIV(144) EX3 QISS2 PCHAIN(6) WAITEX TN(12,13) TN(14,15) TN(16,17) TM(18,19,a3_18,3) ALLQ POWN(a3_18,18,19,3)
#define S19                   BSTB(4) BUD19 BSTE PIV(152) EX3 QISS2 PCHAIN(6) WAITEX TN(12,13) TN(14,15) TN(16,17) TM(18,19,a3_19,4) ALLQ POWN(a3_19,18,19,4)

__global__ __launch_bounds__(256, 3)
void negf_all(const float* __restrict__ tri,
              const float* __restrict__ GL,
              const float* __restrict__ GR,
              float* __restrict__ out)
{
    // 4 independent waves/block, each with a private 1024-float LDS slice:
    // [0,400) Hcm col-major | [400,420) sgL | [420,440) sgR | [448,976) stage
    __shared__ __align__(16) float lds[4][1024];

    f32x2 A0[5], A1[10], A2[15], A3[20];
    unsigned ab, abm, vmu;

    {   // ---- pre-asm scope: everything here dies before the asm ----
        const int tid   = threadIdx.x;
        const int wid   = tid >> 6;
        const int lane  = tid & 63;
        const int w     = blockIdx.x * 4 + wid;
        const int b     = w / 9;
        const int chunk = w - b * 9;

        float* const Hcm = &lds[wid][0];
        float* const sgL = &lds[wid][400];
        float* const sgR = &lds[wid][420];

        const float* triB = tri + b * 210;
        for (int u = lane; u < 400; u += 64) {
            int c = u / 20, r = u - c * 20;
            int lo = r < c ? r : c;
            int hi = r < c ? c : r;
            Hcm[u] = triB[triIdx(lo, hi)];
        }
        if (lane < H_N) { sgL[lane] = GL[b * H_N + lane]; sgR[lane] = GR[b * H_N + lane]; }
        asm volatile("s_waitcnt lgkmcnt(0)" ::: "memory");   // wave-coherent LDS

        if (chunk == 0) {   // H output (row-major, exact copy); one wave per b
            for (int u = lane; u < 400; u += 64) {
                int r = u / 20, c = u - r * 20;
                out[H_OFF + b * 400 + u] = Hcm[c * 20 + r];
            }
        }

        const int sgw = lane / 5;              // 0..11 active, 12 idle
        const int m   = lane - sgw * 5;        // 0..4
        const int e   = chunk * 12 + sgw;
        if (sgw >= 12 || e >= NE) return;

        const int j0 = m, j1 = 5 + m, j2 = 10 + m, j3 = 15 + m;
        const float gam0 = 0.5f * (sgL[j0] + sgR[j0]);
        const float gam1 = 0.5f * (sgL[j1] + sgR[j1]);
        const float gam2 = 0.5f * (sgL[j2] + sgR[j2]);
        const float gam3 = 0.5f * (sgL[j3] + sgR[j3]);
        const float E = fmaf((float)e, 6.0f / 99.0f, -3.0f);

#define MK(DST, I, J, G) { \
        float h = Hcm[(J) * 20 + (I)]; \
        bool vl = (I) <= (J); bool dg = (I) == (J); \
        DST.x = vl ? (dg ? (E - h) : -h) : 0.0f; \
        DST.y = vl ? (dg ? (G) : 0.0f) : 0.0f; }
        #pragma unroll
        for (int i = 0; i < 5;  ++i) MK(A0[i], i, j0, gam0)
        #pragma unroll
        for (int i = 0; i < 10; ++i) MK(A1[i], i, j1, gam1)
        #pragma unroll
        for (int i = 0; i < 15; ++i) MK(A2[i], i, j2, gam2)
        #pragma unroll
        for (int i = 0; i < 20; ++i) MK(A3[i], i, j3, gam3)
#undef MK

        ab  = (unsigned)(size_t)&lds[wid][448] + (unsigned)(sgw * 176);
        abm = ab + 8u * (unsigned)m;
        vmu = (unsigned)m;
    }

    asm volatile(
        "s_waitcnt lgkmcnt(0)\n\t"
        S0 S1 S2 S3 S4 S5 S6 S7 S8 S9
        S10 S11 S12 S13 S14 S15 S16 S17 S18 S19
        : [a0_0]"+v"(A0[0]), [a0_1]"+v"(A0[1]), [a0_2]"+v"(A0[2]), [a0_3]"+v"(A0[3]), [a0_4]"+v"(A0[4]),
          [a1_0]"+v"(A1[0]), [a1_1]"+v"(A1[1]), [a1_2]"+v"(A1[2]), [a1_3]"+v"(A1[3]), [a1_4]"+v"(A1[4]),
          [a1_5]"+v"(A1[5]), [a1_6]"+v"(A1[6]), [a1_7]"+v"(A1[7]), [a1_8]"+v"(A1[8]), [a1_9]"+v"(A1[9]),
          [a2_0]"+v"(A2[0]), [a2_1]"+v"(A2[1]), [a2_2]"+v"(A2[2]), [a2_3]"+v"(A2[3]), [a2_4]"+v"(A2[4]),
          [a2_5]"+v"(A2[5]), [a2_6]"+v"(A2[6]), [a2_7]"+v"(A2[7]), [a2_8]"+v"(A2[8]), [a2_9]"+v"(A2[9]),
          [a2_10]"+v"(A2[10]), [a2_11]"+v"(A2[11]), [a2_12]"+v"(A2[12]), [a2_13]"+v"(A2[13]), [a2_14]"+v"(A2[14]),
          [a3_0]"+v"(A3[0]), [a3_1]"+v"(A3[1]), [a3_2]"+v"(A3[2]), [a3_3]"+v"(A3[3]), [a3_4]"+v"(A3[4]),
          [a3_5]"+v"(A3[5]), [a3_6]"+v"(A3[6]), [a3_7]"+v"(A3[7]), [a3_8]"+v"(A3[8]), [a3_9]"+v"(A3[9]),
          [a3_10]"+v"(A3[10]), [a3_11]"+v"(A3[11]), [a3_12]"+v"(A3[12]), [a3_13]"+v"(A3[13]), [a3_14]"+v"(A3[14]),
          [a3_15]"+v"(A3[15]), [a3_16]"+v"(A3[16]), [a3_17]"+v"(A3[17]), [a3_18]"+v"(A3[18]), [a3_19]"+v"(A3[19]),
          [ab]"+v"(ab), [abm]"+v"(abm), [vm]"+v"(vmu)
        :
        : "vcc", "s90", "s91", "memory",
          "v0","v1","v2","v3","v4","v5","v6","v7","v8","v9",
          "v10","v11","v12","v13","v14","v15","v16","v17","v18","v19",
          "v20");

    // ---- post-asm: launder tid, recompute EVERYTHING (no live-across) ----
    unsigned t2 = (unsigned)threadIdx.x;
    asm("" : "+v"(t2));                        // opaque: breaks CSE with pre-asm
    const int wid2  = (int)(t2 >> 6);
    const int lane2 = (int)(t2 & 63u);
    const int w2    = blockIdx.x * 4 + wid2;
    const int b2    = w2 / 9;
    const int chk2  = w2 - b2 * 9;
    const int sgw2  = lane2 / 5;
    const int m2    = lane2 - sgw2 * 5;
    const int e2    = chk2 * 12 + sgw2;
    float* const sgL2 = &lds[wid2][400];
    float* const sgR2 = &lds[wid2][420];
    const int j0 = m2, j1 = 5 + m2, j2 = 10 + m2, j3 = 15 + m2;

    // ---- epilogue: triangle-weighted T + diag Im, 5-lane reduce ----
    // G symmetric at end: T = sum_{i<=j} |G_ij|^2 (gL_i gR_j + [i<j] gL_j gR_i)
    float tv = 0.0f, dv = 0.0f;
    const float gRj0 = sgR2[j0], gRj1 = sgR2[j1], gRj2 = sgR2[j2], gRj3 = sgR2[j3];
    const float gLj0 = sgL2[j0], gLj1 = sgL2[j1], gLj2 = sgL2[j2], gLj3 = sgL2[j3];
#define ACC(A, I, J, GRJ, GLJ) { \
        float mag = fmaf(A.x, A.x, A.y * A.y); \
        float w3 = ((I) <= (J)) ? fmaf(sgL2[I], GRJ, ((I) < (J)) ? GLJ * sgR2[I] : 0.0f) : 0.0f; \
        tv = fmaf(mag, w3, tv); \
        dv += ((I) == (J)) ? A.y : 0.0f; }
    #pragma unroll
    for (int i = 0; i < 5;  ++i) ACC(A0[i], i, j0, gRj0, gLj0)
    #pragma unroll
    for (int i = 0; i < 10; ++i) ACC(A1[i], i, j1, gRj1, gLj1)
    #pragma unroll
    for (int i = 0; i < 15; ++i) ACC(A2[i], i, j2, gRj2, gLj2)
    #pragma unroll
    for (int i = 0; i < 20; ++i) ACC(A3[i], i, j3, gRj3, gLj3)
#undef ACC

    #pragma unroll
    for (int d = 4; d >= 1; d >>= 1) {
        float tt = __shfl(tv, lane2 + d, 64);
        float dd = __shfl(dv, lane2 + d, 64);
        if (m2 + d < 5) { tv += tt; dv += dd; }
    }
    if (m2 == 0) {
        out[T_OFF + b2 * NE + e2] = __log10f(fmaxf(tv, 1e-16f));
        out[D_OFF + b2 * NE + e2] = __log10f(fmaxf(-dv, 1e-16f));
    }
}

extern "C" void kernel_launch(void* const* d_in, const int* in_sizes, int n_in,
                              void* d_out, int out_size, void* d_ws, size_t ws_size,
                              hipStream_t stream) {
    const float* tri = (const float*)d_in[0];
    const float* gL  = (const float*)d_in[1];
    const float* gR  = (const float*)d_in[2];
    float* out = (float*)d_out;
    negf_all<<<2304, 256, 0, stream>>>(tri, gL, gR, out);
}